// Round 1
// baseline (702.521 us; speedup 1.0000x reference)
//
#include <hip/hip_runtime.h>
#include <hip/hip_bf16.h>
#include <stdint.h>

#define NEXP 8
#define DM   1024
#define HID  4096
#define NTOK 8192
#define CAPS 2048   // expert capacity = K*ceil(N/E) = 2*1024

typedef __attribute__((ext_vector_type(8))) short bh8_t;
typedef __attribute__((ext_vector_type(4))) float f32x4_t;

static __device__ __forceinline__ unsigned short f2bf(float f) {
    __hip_bfloat16 h = __float2bfloat16(f);
    return __builtin_bit_cast(unsigned short, h);
}
static __device__ __forceinline__ float bf2f(unsigned short u) {
    unsigned int x = ((unsigned int)u) << 16;
    return __builtin_bit_cast(float, x);
}

// ---------------- fp32 -> bf16 elementwise convert (fc1 weights) ----------------
__global__ __launch_bounds__(256) void k_conv_bf16(const float* __restrict__ in,
                                                   unsigned short* __restrict__ out, long n) {
    long i = ((long)blockIdx.x * 256 + threadIdx.x) * 4;
    if (i >= n) return;
    float4 v = *(const float4*)(in + i);
    ushort4 o;
    o.x = f2bf(v.x); o.y = f2bf(v.y); o.z = f2bf(v.z); o.w = f2bf(v.w);
    *(ushort4*)(out + i) = o;
}

// ---------------- fc2 [E,H,D] f32 -> [E,D,H] bf16 transpose ----------------
__global__ __launch_bounds__(256) void k_transpose_w2(const float* __restrict__ in,
                                                      unsigned short* __restrict__ out) {
    int e = blockIdx.z;
    const float* I = in + (long)e * HID * DM;
    unsigned short* O = out + (long)e * DM * HID;
    __shared__ float t[32][33];
    int x = threadIdx.x & 31, y = threadIdx.x >> 5;   // 32 x 8
    int h0 = blockIdx.x * 32, d0 = blockIdx.y * 32;
    #pragma unroll
    for (int i = 0; i < 4; ++i)
        t[y + 8*i][x] = I[(long)(h0 + y + 8*i) * DM + d0 + x];
    __syncthreads();
    #pragma unroll
    for (int i = 0; i < 4; ++i)
        O[(long)(d0 + y + 8*i) * HID + h0 + x] = f2bf(t[x][y + 8*i]);
}

// ---------------- gating: logits, softmax, top-2, normalized gates ----------------
__global__ __launch_bounds__(256) void k_gating(const float* __restrict__ x,
        const float* __restrict__ gw, int* __restrict__ topi, float* __restrict__ gates) {
    __shared__ float sg[NEXP][DM];   // 32 KB
    int tid = threadIdx.x;
    for (int i = tid; i < NEXP*DM; i += 256) ((float*)sg)[i] = gw[i];
    __syncthreads();
    int lane = tid & 63, w = tid >> 6;
    long n = (long)blockIdx.x * 4 + w;            // one token per wave
    const float* xr = x + n * DM;
    float acc[NEXP] = {};
    for (int i = 0; i < DM/64; ++i) {
        float xv = xr[lane + i*64];
        #pragma unroll
        for (int e = 0; e < NEXP; ++e) acc[e] += xv * sg[e][lane + i*64];
    }
    #pragma unroll
    for (int e = 0; e < NEXP; ++e)
        #pragma unroll
        for (int off = 32; off; off >>= 1) acc[e] += __shfl_xor(acc[e], off);
    if (lane == 0) {
        float mx = acc[0];
        #pragma unroll
        for (int e = 1; e < NEXP; ++e) mx = fmaxf(mx, acc[e]);
        float p[NEXP];
        #pragma unroll
        for (int e = 0; e < NEXP; ++e) p[e] = expf(acc[e] - mx);
        // top-1 (strict > keeps lowest index on tie, matching lax.top_k)
        float v0 = p[0]; int i0 = 0;
        #pragma unroll
        for (int e = 1; e < NEXP; ++e) if (p[e] > v0) { v0 = p[e]; i0 = e; }
        float v1 = -1.f; int i1 = 0;
        #pragma unroll
        for (int e = 0; e < NEXP; ++e) if (e != i0 && p[e] > v1) { v1 = p[e]; i1 = e; }
        float tot = v0 + v1;
        topi[n*2]   = i0; topi[n*2+1] = i1;
        gates[n*2]  = v0 / tot; gates[n*2+1] = v1 / tot;
    }
}

// ---------------- capacity locations (exact sequential cumsum semantics) ----------------
__global__ __launch_bounds__(64) void k_locate(const int* __restrict__ topi,
                                               int* __restrict__ flat) {
    int lane = threadIdx.x;
    const int TPL = NTOK / 64;     // 128 consecutive tokens per lane
    int base = lane * TPL;
    int offset[NEXP];
    #pragma unroll
    for (int e = 0; e < NEXP; ++e) offset[e] = 0;
    for (int j = 0; j < 2; ++j) {
        // pass A: per-lane counts, packed 8x8-bit (<=128 per lane fits)
        unsigned long long pk = 0;
        for (int t = 0; t < TPL; ++t) {
            int e = topi[(long)(base + t)*2 + j];
            pk += 1ull << (8*e);
        }
        int cnt[NEXP], excl[NEXP];
        #pragma unroll
        for (int e = 0; e < NEXP; ++e) cnt[e] = (int)((pk >> (8*e)) & 0xff);
        #pragma unroll
        for (int e = 0; e < NEXP; ++e) {
            int v = cnt[e];
            for (int d = 1; d < 64; d <<= 1) {
                int o = __shfl_up(v, d);
                if (lane >= d) v += o;
            }
            excl[e] = v - cnt[e] + offset[e];
            offset[e] += __shfl(v, 63);
        }
        // pass B: assign locations; counters packed 16-bit in two u64s (no
        // runtime-indexed array -> stays in registers)
        unsigned long long lo = 0, hi = 0;
        #pragma unroll
        for (int e = 0; e < 4; ++e)    lo |= (unsigned long long)(excl[e] & 0xffff) << (16*e);
        #pragma unroll
        for (int e = 4; e < NEXP; ++e) hi |= (unsigned long long)(excl[e] & 0xffff) << (16*(e-4));
        for (int t = 0; t < TPL; ++t) {
            long n = base + t;
            int e = topi[n*2 + j];
            int sh = 16 * (e & 3);
            int loc;
            if (e < 4) { loc = (int)((lo >> sh) & 0xffff); lo += 1ull << sh; }
            else       { loc = (int)((hi >> sh) & 0xffff); hi += 1ull << sh; }
            flat[n*2 + j] = (loc < CAPS) ? (e * CAPS + loc) : -1;
        }
    }
}

// ---------------- dispatch: scatter tokens (bf16) into [E*cap, D] ----------------
__global__ __launch_bounds__(256) void k_dispatch(const float* __restrict__ x,
        const int* __restrict__ flat, unsigned short* __restrict__ disp) {
    long n = blockIdx.x;
    int tid = threadIdx.x;
    float4 v = *(const float4*)(x + n*DM + tid*4);
    ushort4 o; o.x = f2bf(v.x); o.y = f2bf(v.y); o.z = f2bf(v.z); o.w = f2bf(v.w);
    int f0 = flat[n*2], f1 = flat[n*2+1];
    if (f0 >= 0) *(ushort4*)(disp + (long)f0*DM + tid*4) = o;
    if (f1 >= 0) *(ushort4*)(disp + (long)f1*DM + tid*4) = o;
}

// ---------------- bf16 MFMA GEMM:  C[M,N] = A[M,K] * B[N,K]^T  (+bias, opt. relu) ----------------
#define BM 128
#define BN 128
#define BKK 64

template<int RELU>
__global__ __launch_bounds__(256)
void k_gemm(const unsigned short* __restrict__ A, const unsigned short* __restrict__ B,
            const float* __restrict__ bias, unsigned short* __restrict__ C,
            int M, int N, int Kd, long strA, long strB, long strBias, long strC)
{
    int e = blockIdx.z;
    A += (long)e * strA; B += (long)e * strB; C += (long)e * strC;
    const float* bi = bias + (long)e * strBias;

    __shared__ unsigned short sA[BM*BKK];
    __shared__ unsigned short sB[BN*BKK];

    int tid = threadIdx.x;
    int wid = tid >> 6, lane = tid & 63;
    int wr = wid >> 1, wc = wid & 1;          // 2x2 waves of 64x64
    long tm = (long)blockIdx.y * BM;
    long tn = (long)blockIdx.x * BN;

    f32x4_t acc[4][4] = {};

    // staging geometry: per wave-chunk, lane l covers 16B at LDS base + l*16
    int r0 = wid*32 + (lane >> 3);            // + c*8
    int sc = (lane & 7) * 8;
    const unsigned short* Abase = A + tm*Kd + sc;
    const unsigned short* Bbase = B + tn*Kd + sc;

    for (int k0 = 0; k0 < Kd; k0 += BKK) {
        #pragma unroll
        for (int c = 0; c < 4; ++c) {
            int r = r0 + c*8;
            __builtin_amdgcn_global_load_lds(
                (const __attribute__((address_space(1))) void*)(Abase + (long)r*Kd + k0),
                (__attribute__((address_space(3))) void*)(sA + r*BKK + sc), 16, 0, 0);
            __builtin_amdgcn_global_load_lds(
                (const __attribute__((address_space(1))) void*)(Bbase + (long)r*Kd + k0),
                (__attribute__((address_space(3))) void*)(sB + r*BKK + sc), 16, 0, 0);
        }
        __syncthreads();
        int am = wr*64 + (lane & 15);
        int bn = wc*64 + (lane & 15);
        int kq = (lane >> 4) * 8;
        #pragma unroll
        for (int kk = 0; kk < 2; ++kk) {
            bh8_t av[4], bv[4];
            #pragma unroll
            for (int i = 0; i < 4; ++i) {
                av[i] = *(const bh8_t*)(sA + (am + i*16)*BKK + kk*32 + kq);
                bv[i] = *(const bh8_t*)(sB + (bn + i*16)*BKK + kk*32 + kq);
            }
            #pragma unroll
            for (int mi = 0; mi < 4; ++mi)
                #pragma unroll
                for (int ni = 0; ni < 4; ++ni)
                    acc[mi][ni] = __builtin_amdgcn_mfma_f32_16x16x32_bf16(
                        av[mi], bv[ni], acc[mi][ni], 0, 0, 0);
        }
        __syncthreads();
    }

    // epilogue: C/D layout col=lane&15, row=(lane>>4)*4+reg  (m89-verified)
    int or0 = wr*64 + (lane >> 4) * 4;
    int oc0 = wc*64 + (lane & 15);
    #pragma unroll
    for (int ni = 0; ni < 4; ++ni) {
        long col = tn + oc0 + ni*16;
        float bv = bi[col];
        #pragma unroll
        for (int mi = 0; mi < 4; ++mi) {
            #pragma unroll
            for (int r = 0; r < 4; ++r) {
                long row = tm + or0 + mi*16 + r;
                float v = acc[mi][ni][r] + bv;
                if (RELU) v = fmaxf(v, 0.f);
                C[row * N + col] = f2bf(v);
            }
        }
    }
}

// ---------------- combine: out[n] = sum_j gate_j * eo[flat_j] ----------------
__global__ __launch_bounds__(256) void k_combine(const unsigned short* __restrict__ eo,
        const int* __restrict__ flat, const float* __restrict__ gates,
        float* __restrict__ out) {
    long n = blockIdx.x;
    int tid = threadIdx.x;
    int f0 = flat[n*2], f1 = flat[n*2+1];
    float g0 = (f0 >= 0) ? gates[n*2]   : 0.f;
    float g1 = (f1 >= 0) ? gates[n*2+1] : 0.f;
    const unsigned short* r0 = eo + (long)(f0 >= 0 ? f0 : 0) * DM;
    const unsigned short* r1 = eo + (long)(f1 >= 0 ? f1 : 0) * DM;
    ushort4 a = *(const ushort4*)(r0 + tid*4);
    ushort4 b = *(const ushort4*)(r1 + tid*4);
    float4 o;
    o.x = g0*bf2f(a.x) + g1*bf2f(b.x);
    o.y = g0*bf2f(a.y) + g1*bf2f(b.y);
    o.z = g0*bf2f(a.z) + g1*bf2f(b.z);
    o.w = g0*bf2f(a.w) + g1*bf2f(b.w);
    *(float4*)(out + n*DM + tid*4) = o;
}

extern "C" void kernel_launch(void* const* d_in, const int* in_sizes, int n_in,
                              void* d_out, int out_size, void* d_ws, size_t ws_size,
                              hipStream_t stream) {
    const float* x    = (const float*)d_in[0];
    const float* gw   = (const float*)d_in[1];
    const float* fc1w = (const float*)d_in[2];
    const float* fc1b = (const float*)d_in[3];
    const float* fc2w = (const float*)d_in[4];
    const float* fc2b = (const float*)d_in[5];
    float* out = (float*)d_out;
    char* ws = (char*)d_ws;

    // ws layout (bytes):
    //   [0,   32MB) disp bf16 [E*cap, D]   (later aliased by eo)
    //   [32, 160MB) h    bf16 [E*cap, H]
    //   [160,224MB) w1b  bf16 [E, H, D]
    //   [224,288MB) w2t  bf16 [E, D, H]
    //   [288MB, ..) topi / gates / flat
    unsigned short* disp = (unsigned short*)(ws);
    unsigned short* eo   = disp;                                   // alias: disp dead after GEMM1
    unsigned short* h    = (unsigned short*)(ws + 33554432L);
    unsigned short* w1b  = (unsigned short*)(ws + 33554432L + 134217728L);
    unsigned short* w2t  = (unsigned short*)(ws + 33554432L + 134217728L + 67108864L);
    char* tail           = ws + 33554432L + 134217728L + 67108864L + 67108864L;
    int*   topi  = (int*)tail;
    float* gates = (float*)(tail + 65536);
    int*   flat  = (int*)(tail + 131072);

    long n1 = (long)NEXP * HID * DM;

    hipMemsetAsync(disp, 0, (size_t)NEXP * CAPS * DM * 2, stream);
    k_conv_bf16<<<dim3(n1/1024), 256, 0, stream>>>(fc1w, w1b, n1);
    k_transpose_w2<<<dim3(HID/32, DM/32, NEXP), 256, 0, stream>>>(fc2w, w2t);
    k_gating<<<dim3(NTOK/4), 256, 0, stream>>>(x, gw, topi, gates);
    k_locate<<<dim3(1), 64, 0, stream>>>(topi, flat);
    k_dispatch<<<dim3(NTOK), 256, 0, stream>>>(x, flat, disp);
    k_gemm<1><<<dim3(HID/BN, CAPS/BM, NEXP), 256, 0, stream>>>(
        disp, w1b, fc1b, h, CAPS, HID, DM,
        (long)CAPS*DM, (long)HID*DM, (long)HID, (long)CAPS*HID);
    k_gemm<0><<<dim3(DM/BN, CAPS/BM, NEXP), 256, 0, stream>>>(
        h, w2t, fc2b, eo, CAPS, DM, HID,
        (long)CAPS*HID, (long)DM*HID, (long)DM, (long)CAPS*DM);
    k_combine<<<dim3(NTOK), 256, 0, stream>>>(eo, flat, gates, out);
}

// Round 2
// 471.873 us; speedup vs baseline: 1.4888x; 1.4888x over previous
//
#include <hip/hip_runtime.h>
#include <hip/hip_bf16.h>
#include <stdint.h>

#define NEXP 8
#define DM   1024
#define HID  4096
#define NTOK 8192
#define CAPS 2048   // expert capacity = K*ceil(N/E) = 2*1024

#define BM 256
#define BN 256
#define BK 64

typedef __attribute__((ext_vector_type(8))) short bh8_t;
typedef __attribute__((ext_vector_type(4))) float f32x4_t;
typedef unsigned short u16;

static __device__ __forceinline__ u16 f2bf(float f) {
    __hip_bfloat16 h = __float2bfloat16(f);
    return __builtin_bit_cast(u16, h);
}
static __device__ __forceinline__ float bf2f(u16 u) {
    unsigned int x = ((unsigned int)u) << 16;
    return __builtin_bit_cast(float, x);
}

#define FENCE asm volatile("" ::: "memory")
#define BAR   do { FENCE; __builtin_amdgcn_s_barrier(); FENCE; } while (0)
#define LGKM0 do { asm volatile("s_waitcnt lgkmcnt(0)" ::: "memory"); \
                   __builtin_amdgcn_sched_barrier(0); } while (0)
#define MFMA(d, a, b) d = __builtin_amdgcn_mfma_f32_16x16x32_bf16(a, b, d, 0, 0, 0)

// ---------------- fp32 -> bf16 elementwise convert (fc1 weights) ----------------
__global__ __launch_bounds__(256) void k_conv_bf16(const float* __restrict__ in,
                                                   u16* __restrict__ out, long n) {
    long i = ((long)blockIdx.x * 256 + threadIdx.x) * 4;
    if (i >= n) return;
    float4 v = *(const float4*)(in + i);
    ushort4 o;
    o.x = f2bf(v.x); o.y = f2bf(v.y); o.z = f2bf(v.z); o.w = f2bf(v.w);
    *(ushort4*)(out + i) = o;
}

// ---------------- fc2 [E,H,D] f32 -> [E,D,H] bf16 transpose ----------------
__global__ __launch_bounds__(256) void k_transpose_w2(const float* __restrict__ in,
                                                      u16* __restrict__ out) {
    int e = blockIdx.z;
    const float* I = in + (long)e * HID * DM;
    u16* O = out + (long)e * DM * HID;
    __shared__ float t[32][33];
    int x = threadIdx.x & 31, y = threadIdx.x >> 5;   // 32 x 8
    int h0 = blockIdx.x * 32, d0 = blockIdx.y * 32;
    #pragma unroll
    for (int i = 0; i < 4; ++i)
        t[y + 8*i][x] = I[(long)(h0 + y + 8*i) * DM + d0 + x];
    __syncthreads();
    #pragma unroll
    for (int i = 0; i < 4; ++i)
        O[(long)(d0 + y + 8*i) * HID + h0 + x] = f2bf(t[x][y + 8*i]);
}

// ---------------- gating: logits, softmax, top-2, normalized gates ----------------
__global__ __launch_bounds__(256) void k_gating(const float* __restrict__ x,
        const float* __restrict__ gw, int* __restrict__ topi, float* __restrict__ gates) {
    __shared__ float sg[NEXP][DM];   // 32 KB
    int tid = threadIdx.x;
    for (int i = tid; i < NEXP*DM; i += 256) ((float*)sg)[i] = gw[i];
    __syncthreads();
    int lane = tid & 63, w = tid >> 6;
    long n = (long)blockIdx.x * 4 + w;            // one token per wave
    const float* xr = x + n * DM;
    float acc[NEXP] = {};
    for (int i = 0; i < DM/64; ++i) {
        float xv = xr[lane + i*64];
        #pragma unroll
        for (int e = 0; e < NEXP; ++e) acc[e] += xv * sg[e][lane + i*64];
    }
    #pragma unroll
    for (int e = 0; e < NEXP; ++e)
        #pragma unroll
        for (int off = 32; off; off >>= 1) acc[e] += __shfl_xor(acc[e], off);
    if (lane == 0) {
        float mx = acc[0];
        #pragma unroll
        for (int e = 1; e < NEXP; ++e) mx = fmaxf(mx, acc[e]);
        float p[NEXP];
        #pragma unroll
        for (int e = 0; e < NEXP; ++e) p[e] = expf(acc[e] - mx);
        float v0 = p[0]; int i0 = 0;
        #pragma unroll
        for (int e = 1; e < NEXP; ++e) if (p[e] > v0) { v0 = p[e]; i0 = e; }
        float v1 = -1.f; int i1 = 0;
        #pragma unroll
        for (int e = 0; e < NEXP; ++e) if (e != i0 && p[e] > v1) { v1 = p[e]; i1 = e; }
        float tot = v0 + v1;
        topi[n*2]   = i0; topi[n*2+1] = i1;
        gates[n*2]  = v0 / tot; gates[n*2+1] = v1 / tot;
    }
}

// ---------------- capacity locations (exact sequential cumsum semantics) ----------------
__global__ __launch_bounds__(64) void k_locate(const int* __restrict__ topi,
                                               int* __restrict__ flat) {
    int lane = threadIdx.x;
    const int TPL = NTOK / 64;     // 128 consecutive tokens per lane
    int base = lane * TPL;
    int offset[NEXP];
    #pragma unroll
    for (int e = 0; e < NEXP; ++e) offset[e] = 0;
    for (int j = 0; j < 2; ++j) {
        unsigned long long pk = 0;
        for (int t = 0; t < TPL; ++t) {
            int e = topi[(long)(base + t)*2 + j];
            pk += 1ull << (8*e);
        }
        int cnt[NEXP], excl[NEXP];
        #pragma unroll
        for (int e = 0; e < NEXP; ++e) cnt[e] = (int)((pk >> (8*e)) & 0xff);
        #pragma unroll
        for (int e = 0; e < NEXP; ++e) {
            int v = cnt[e];
            for (int d = 1; d < 64; d <<= 1) {
                int o = __shfl_up(v, d);
                if (lane >= d) v += o;
            }
            excl[e] = v - cnt[e] + offset[e];
            offset[e] += __shfl(v, 63);
        }
        unsigned long long lo = 0, hi = 0;
        #pragma unroll
        for (int e = 0; e < 4; ++e)    lo |= (unsigned long long)(excl[e] & 0xffff) << (16*e);
        #pragma unroll
        for (int e = 4; e < NEXP; ++e) hi |= (unsigned long long)(excl[e] & 0xffff) << (16*(e-4));
        for (int t = 0; t < TPL; ++t) {
            long n = base + t;
            int e = topi[n*2 + j];
            int sh = 16 * (e & 3);
            int loc;
            if (e < 4) { loc = (int)((lo >> sh) & 0xffff); lo += 1ull << sh; }
            else       { loc = (int)((hi >> sh) & 0xffff); hi += 1ull << sh; }
            flat[n*2 + j] = (loc < CAPS) ? (e * CAPS + loc) : -1;
        }
    }
}

// ---------------- dispatch: scatter tokens (bf16) into [E*cap, D] ----------------
__global__ __launch_bounds__(256) void k_dispatch(const float* __restrict__ x,
        const int* __restrict__ flat, u16* __restrict__ disp) {
    long n = blockIdx.x;
    int tid = threadIdx.x;
    float4 v = *(const float4*)(x + n*DM + tid*4);
    ushort4 o; o.x = f2bf(v.x); o.y = f2bf(v.y); o.z = f2bf(v.z); o.w = f2bf(v.w);
    int f0 = flat[n*2], f1 = flat[n*2+1];
    if (f0 >= 0) *(ushort4*)(disp + (long)f0*DM + tid*4) = o;
    if (f1 >= 0) *(ushort4*)(disp + (long)f1*DM + tid*4) = o;
}

// ---------------- staging: one 16KB half-region (128 rows x 64 cols bf16) ----------
// LDS dest linear (base + lane*16); global source pre-swizzled with the inverse of
// the read-side XOR  byte ^= ((row&7)<<4)   (rule #21: both-sides-or-neither).
static __device__ __forceinline__ void stage_half(const u16* __restrict__ g, int ld,
                                                  u16* R, int wid, int lane) {
    int rlo = wid*8 + (lane >> 3);                       // rows 0..63 (q=0), +64 (q=1)
    int cbe = ((lane & 7) ^ ((lane >> 3) & 7)) * 8;      // swizzled source col (elems)
    const u16* s0 = g + (long)rlo * ld + cbe;
    const u16* s1 = g + (long)(rlo + 64) * ld + cbe;
    u16* d0 = R + wid*512 + lane*8;
    u16* d1 = R + 4096 + wid*512 + lane*8;
    __builtin_amdgcn_global_load_lds((const __attribute__((address_space(1))) void*)s0,
        (__attribute__((address_space(3))) void*)d0, 16, 0, 0);
    __builtin_amdgcn_global_load_lds((const __attribute__((address_space(1))) void*)s1,
        (__attribute__((address_space(3))) void*)d1, 16, 0, 0);
}

// ---------------- 256x256 8-phase bf16 MFMA GEMM:  C[M,N] = A[M,K]*B[N,K]^T + bias --
template<int RELU>
__global__ __launch_bounds__(512, 2)
void k_gemm8(const u16* __restrict__ A, const u16* __restrict__ B,
             const float* __restrict__ bias, u16* __restrict__ C,
             int N, int K, long strA, long strB, long strBias, long strC)
{
    __shared__ u16 sm[2][2][2][8192];   // [buf][A=0/B=1][half][128*64] = 128 KiB

    // T1: XCD-aware bijective remap of linear block id (nwg % 8 == 0 for our grids)
    int gx = gridDim.x, gy = gridDim.y;
    int nwg = gx * gy * (int)gridDim.z;
    int lin = blockIdx.x + gx * (blockIdx.y + gy * blockIdx.z);
    int qq  = nwg >> 3;
    int swz = (lin & 7) * qq + (lin >> 3);
    int gxy = gx * gy;
    int bz = swz / gxy, rm = swz % gxy, by = rm / gx, bx = rm % gx;

    const u16* Ae = A + (long)bz * strA;
    const u16* Be = B + (long)bz * strB;
    const float* bi = bias + (long)bz * strBias;
    u16* Ce = C + (long)bz * strC;

    long tm = (long)by * BM, tn = (long)bx * BN;
    const u16* Abase = Ae + tm * (long)K;
    const u16* Bbase = Be + tn * (long)K;

    int tid = threadIdx.x, lane = tid & 63, wid = tid >> 6;
    int wr = wid >> 2, wc = wid & 3;            // 2x4 waves of 128x64 output

    int frow = lane & 15;
    int fc0 = (((lane >> 4) * 16)      ^ ((lane & 7) << 4)) >> 1;   // kk=0 col (elems)
    int fc1 = ((64 + (lane >> 4) * 16) ^ ((lane & 7) << 4)) >> 1;   // kk=1

    const int NT = K / BK;

    f32x4_t acc[8][4] = {};

    auto STG = [&](int buf, int ab, int half, int kt) {
        const u16* g = (ab ? Bbase : Abase) + (long)(half * 128) * K + (long)kt * BK;
        stage_half(g, K, &sm[buf][ab][half][0], wid, lane);
    };
    auto LDA = [&](int c, int mi, int kk) -> bh8_t {
        const u16* p = &sm[c][0][wr][0] + (mi * 16 + frow) * 64 + (kk ? fc1 : fc0);
        return *(const bh8_t*)p;
    };
    auto LDB = [&](int c, int ni, int kk) -> bh8_t {
        const u16* p = &sm[c][1][wc >> 1][0] + ((wc & 1) * 64 + ni * 16 + frow) * 64 + (kk ? fc1 : fc0);
        return *(const bh8_t*)p;
    };

    // 4 phases/K-tile; region free-schedule: B0,B1 consumed by ph2, A0,A1 by ph3.
    // Stages: ph1 -> (kt+1).A1 [buf c^1], ph2 -> (kt+1).B1, ph3 -> (kt+2).B0 [buf c],
    // ph4 -> (kt+2).A0; vmcnt(4) once per K-tile at ph4 (kt+2's B0,A0 stay in flight).
    auto ktile = [&](int c, int kt, int s12, int s34, int vm) {
        bh8_t a0[4][2], a1[4][2], bf[4][2];
        // ---- phase 1: read A-mh0 + B-nh0 (12 reads); MFMA Q(0,0)
        #pragma unroll
        for (int mi = 0; mi < 4; ++mi) { a0[mi][0] = LDA(c, mi, 0); a0[mi][1] = LDA(c, mi, 1); }
        #pragma unroll
        for (int ni = 0; ni < 2; ++ni) { bf[ni][0] = LDB(c, ni, 0); bf[ni][1] = LDB(c, ni, 1); }
        if (s12) STG(c ^ 1, 0, 1, kt + 1);
        BAR; LGKM0;
        __builtin_amdgcn_s_setprio(1);
        #pragma unroll
        for (int mi = 0; mi < 4; ++mi)
            #pragma unroll
            for (int ni = 0; ni < 2; ++ni)
                #pragma unroll
                for (int kk = 0; kk < 2; ++kk) MFMA(acc[mi][ni], a0[mi][kk], bf[ni][kk]);
        __builtin_amdgcn_s_setprio(0);
        __builtin_amdgcn_sched_barrier(0);
        BAR;
        // ---- phase 2: read B-nh1 (4 reads); MFMA Q(0,1)
        #pragma unroll
        for (int ni = 2; ni < 4; ++ni) { bf[ni][0] = LDB(c, ni, 0); bf[ni][1] = LDB(c, ni, 1); }
        if (s12) STG(c ^ 1, 1, 1, kt + 1);
        BAR; LGKM0;
        __builtin_amdgcn_s_setprio(1);
        #pragma unroll
        for (int mi = 0; mi < 4; ++mi)
            #pragma unroll
            for (int ni = 2; ni < 4; ++ni)
                #pragma unroll
                for (int kk = 0; kk < 2; ++kk) MFMA(acc[mi][ni], a0[mi][kk], bf[ni][kk]);
        __builtin_amdgcn_s_setprio(0);
        __builtin_amdgcn_sched_barrier(0);
        BAR;
        // ---- phase 3: read A-mh1 (8 reads); MFMA Q(1,0)
        #pragma unroll
        for (int mi = 0; mi < 4; ++mi) { a1[mi][0] = LDA(c, mi + 4, 0); a1[mi][1] = LDA(c, mi + 4, 1); }
        if (s34) STG(c, 1, 0, kt + 2);
        BAR; LGKM0;
        __builtin_amdgcn_s_setprio(1);
        #pragma unroll
        for (int mi = 0; mi < 4; ++mi)
            #pragma unroll
            for (int ni = 0; ni < 2; ++ni)
                #pragma unroll
                for (int kk = 0; kk < 2; ++kk) MFMA(acc[mi + 4][ni], a1[mi][kk], bf[ni][kk]);
        __builtin_amdgcn_s_setprio(0);
        __builtin_amdgcn_sched_barrier(0);
        BAR;
        // ---- phase 4: stage + vmcnt; MFMA Q(1,1)
        if (s34) STG(c, 0, 0, kt + 2);
        if (vm == 4)      { asm volatile("s_waitcnt vmcnt(4)" ::: "memory"); }
        else if (vm == 0) { asm volatile("s_waitcnt vmcnt(0)" ::: "memory"); }
        BAR; LGKM0;
        __builtin_amdgcn_s_setprio(1);
        #pragma unroll
        for (int mi = 0; mi < 4; ++mi)
            #pragma unroll
            for (int ni = 2; ni < 4; ++ni)
                #pragma unroll
                for (int kk = 0; kk < 2; ++kk) MFMA(acc[mi + 4][ni], a1[mi][kk], bf[ni][kk]);
        __builtin_amdgcn_s_setprio(0);
        __builtin_amdgcn_sched_barrier(0);
        BAR;
    };

    // prologue: kt0 fully, kt1 B0+A0; wait kt0 landed (kt1's 4 loads in flight)
    STG(0, 0, 0, 0); STG(0, 0, 1, 0); STG(0, 1, 0, 0); STG(0, 1, 1, 0);
    STG(1, 1, 0, 1); STG(1, 0, 0, 1);
    asm volatile("s_waitcnt vmcnt(4)" ::: "memory");
    BAR;

    int kt = 0;
    for (; kt < NT - 2; ++kt) ktile(kt & 1, kt, 1, 1, 4);
    ktile(kt & 1, kt, 1, 0, 0); ++kt;   // NT-2: stage (NT-1).A1/B1, drain
    ktile(kt & 1, kt, 0, 0, -1);        // NT-1: compute only

    // ---- epilogue: acc -> LDS bounce (swizzled) -> coalesced 16B global stores ----
    u16* wb = &sm[0][0][0][0] + wid * 8192;
    #pragma unroll
    for (int mi = 0; mi < 8; ++mi)
        #pragma unroll
        for (int ni = 0; ni < 4; ++ni) {
            float bv = bi[tn + wc * 64 + ni * 16 + (lane & 15)];
            #pragma unroll
            for (int r = 0; r < 4; ++r) {
                int row = mi * 16 + (lane >> 4) * 4 + r;
                int ce  = ni * 16 + (lane & 15);
                float v = acc[mi][ni][r] + bv;
                if (RELU) v = fmaxf(v, 0.f);
                wb[row * 64 + (ce ^ ((row & 7) << 3))] = f2bf(v);
            }
        }
    __syncthreads();
    long crow = tm + wr * 128;
    long ccol = tn + wc * 64 + (lane & 7) * 8;
    #pragma unroll
    for (int i = 0; i < 16; ++i) {
        int rr = i * 8 + (lane >> 3);
        bh8_t v = *(const bh8_t*)(wb + rr * 64 + (((lane & 7) * 8) ^ ((rr & 7) << 3)));
        *(bh8_t*)(Ce + (crow + rr) * N + ccol) = v;
    }
}

// ---------------- combine: out[n] = sum_j gate_j * eo[flat_j] ----------------
__global__ __launch_bounds__(256) void k_combine(const u16* __restrict__ eo,
        const int* __restrict__ flat, const float* __restrict__ gates,
        float* __restrict__ out) {
    long n = blockIdx.x;
    int tid = threadIdx.x;
    int f0 = flat[n*2], f1 = flat[n*2+1];
    float g0 = (f0 >= 0) ? gates[n*2]   : 0.f;
    float g1 = (f1 >= 0) ? gates[n*2+1] : 0.f;
    const u16* r0 = eo + (long)(f0 >= 0 ? f0 : 0) * DM;
    const u16* r1 = eo + (long)(f1 >= 0 ? f1 : 0) * DM;
    ushort4 a = *(const ushort4*)(r0 + tid*4);
    ushort4 b = *(const ushort4*)(r1 + tid*4);
    float4 o;
    o.x = g0*bf2f(a.x) + g1*bf2f(b.x);
    o.y = g0*bf2f(a.y) + g1*bf2f(b.y);
    o.z = g0*bf2f(a.z) + g1*bf2f(b.z);
    o.w = g0*bf2f(a.w) + g1*bf2f(b.w);
    *(float4*)(out + n*DM + tid*4) = o;
}

extern "C" void kernel_launch(void* const* d_in, const int* in_sizes, int n_in,
                              void* d_out, int out_size, void* d_ws, size_t ws_size,
                              hipStream_t stream) {
    const float* x    = (const float*)d_in[0];
    const float* gw   = (const float*)d_in[1];
    const float* fc1w = (const float*)d_in[2];
    const float* fc1b = (const float*)d_in[3];
    const float* fc2w = (const float*)d_in[4];
    const float* fc2b = (const float*)d_in[5];
    float* out = (float*)d_out;
    char* ws = (char*)d_ws;

    u16* disp = (u16*)(ws);
    u16* eo   = disp;                                   // alias: disp dead after GEMM1
    u16* h    = (u16*)(ws + 33554432L);
    u16* w1b  = (u16*)(ws + 33554432L + 134217728L);
    u16* w2t  = (u16*)(ws + 33554432L + 134217728L + 67108864L);
    char* tail = ws + 33554432L + 134217728L + 67108864L + 67108864L;
    int*   topi  = (int*)tail;
    float* gates = (float*)(tail + 65536);
    int*   flat  = (int*)(tail + 131072);

    long n1 = (long)NEXP * HID * DM;

    hipMemsetAsync(disp, 0, (size_t)NEXP * CAPS * DM * 2, stream);
    k_conv_bf16<<<dim3(n1/1024), 256, 0, stream>>>(fc1w, w1b, n1);
    k_transpose_w2<<<dim3(HID/32, DM/32, NEXP), 256, 0, stream>>>(fc2w, w2t);
    k_gating<<<dim3(NTOK/4), 256, 0, stream>>>(x, gw, topi, gates);
    k_locate<<<dim3(1), 64, 0, stream>>>(topi, flat);
    k_dispatch<<<dim3(NTOK), 256, 0, stream>>>(x, flat, disp);
    k_gemm8<1><<<dim3(HID/BN, CAPS/BM, NEXP), 512, 0, stream>>>(
        disp, w1b, fc1b, h, HID, DM,
        (long)CAPS*DM, (long)HID*DM, (long)HID, (long)CAPS*HID);
    k_gemm8<0><<<dim3(DM/BN, CAPS/BM, NEXP), 512, 0, stream>>>(
        h, w2t, fc2b, eo, DM, HID,
        (long)CAPS*HID, (long)DM*HID, (long)DM, (long)CAPS*DM);
    k_combine<<<dim3(NTOK), 256, 0, stream>>>(eo, flat, gates, out);
}